// Round 2
// baseline (341.794 us; speedup 1.0000x reference)
//
#include <hip/hip_runtime.h>
#include <math.h>

#define N_NODES 100000
#define E_EDGES 1600000
#define F_IN 32
#define HID 16
#define NC 10
#define SRC_BITS 17
#define SRC_MASK ((1u << SRC_BITS) - 1u)
#define VQ_SCALE 32767.0f
#define DBLK_E 4096                                  // edges per degree-count block
#define NDBLK ((E_EDGES + DBLK_E - 1) / DBLK_E)      // 391
#define NODE_GRID ((N_NODES + 255) / 256)            // 391
#define SCAN_BLK 512
#define NSCAN ((N_NODES + SCAN_BLK - 1) / SCAN_BLK)  // 196

// bf16 pack (RNE) of two floats into one uint: low16 = lo, high16 = hi
__device__ __forceinline__ unsigned int bf16pair(float lo, float hi) {
    unsigned int ulo = __float_as_uint(lo), uhi = __float_as_uint(hi);
    ulo += 0x7fffu + ((ulo >> 16) & 1u);
    uhi += 0x7fffu + ((uhi >> 16) & 1u);
    return (ulo >> 16) | (uhi & 0xffff0000u);
}

__device__ __forceinline__ float lerp_pair(unsigned int pair, float v) {
    float a = __uint_as_float(pair << 16);
    float b = __uint_as_float(pair & 0xffff0000u);
    return fmaf(v, b - a, a);
}

// ------- fused: per-node layer-1 projections (blocks 0..390) + degree count (391..781) -------
__global__ __launch_bounds__(256) void fused_l1deg(
    const float* __restrict__ x, const float* __restrict__ W1,
    const float* __restrict__ root1, const float* __restrict__ b1,
    const int* __restrict__ ei,
    unsigned int* __restrict__ y, float* __restrict__ r1,
    int* __restrict__ deg)
{
    if (blockIdx.x >= NODE_GRID) {
        // ---- degree-count half: global atomics into deg[], int4 loads ----
        int b = blockIdx.x - NODE_GRID;
        const int* dstp = ei + E_EDGES;
        int e0 = b * DBLK_E;
        for (int i = threadIdx.x * 4; i < DBLK_E; i += 1024) {
            int e = e0 + i;
            if (e + 3 < E_EDGES) {
                int4 d4 = *(const int4*)(dstp + e);
                atomicAdd(&deg[d4.x], 1);
                atomicAdd(&deg[d4.y], 1);
                atomicAdd(&deg[d4.z], 1);
                atomicAdd(&deg[d4.w], 1);
            } else {
                for (int k = 0; k < 4; k++)
                    if (e + k < E_EDGES) atomicAdd(&deg[dstp[e + k]], 1);
            }
        }
        return;
    }
    // ---- node_l1 half ----
    __shared__ float sW0[F_IN * HID], sW1[F_IN * HID], sR[F_IN * HID], sB[HID];
    for (int i = threadIdx.x; i < F_IN * HID; i += 256) {
        sW0[i] = W1[i];
        sW1[i] = W1[F_IN * HID + i];
        sR[i]  = root1[i];
    }
    if (threadIdx.x < HID) sB[threadIdx.x] = b1[threadIdx.x];
    __syncthreads();

    int n = blockIdx.x * 256 + threadIdx.x;
    if (n >= N_NODES) return;

    float xr[F_IN];
    const float4* xp = (const float4*)(x + (size_t)n * F_IN);
    #pragma unroll
    for (int i = 0; i < F_IN / 4; i++) {
        float4 t = xp[i];
        xr[i*4+0] = t.x; xr[i*4+1] = t.y; xr[i*4+2] = t.z; xr[i*4+3] = t.w;
    }

    float a0[HID], a1[HID], ar[HID];
    #pragma unroll
    for (int o = 0; o < HID; o++) { a0[o] = 0.f; a1[o] = 0.f; ar[o] = sB[o]; }
    for (int i = 0; i < F_IN; i++) {
        float xi = xr[i];
        #pragma unroll
        for (int o = 0; o < HID; o++) {
            a0[o] += xi * sW0[i * HID + o];
            a1[o] += xi * sW1[i * HID + o];
            ar[o] += xi * sR[i * HID + o];
        }
    }
    unsigned int* py = y + (size_t)n * 16;
    float* pr = r1 + (size_t)n * HID;
    #pragma unroll
    for (int o = 0; o < HID; o++) {
        py[o] = bf16pair(a0[o], a1[o]);
        pr[o] = ar[o];
    }
}

// ---- scan step 1: per-block (512 nodes) exclusive scan of deg; block totals -> part ----
__global__ __launch_bounds__(512) void k_scan1(
    const int* __restrict__ deg, int* __restrict__ start, int* __restrict__ part)
{
    __shared__ int wsum[8], woff[8];
    int t = threadIdx.x;
    int node = blockIdx.x * SCAN_BLK + t;
    int v = (node < N_NODES) ? deg[node] : 0;
    int w = t >> 6, l = t & 63;
    int incl = v;
    #pragma unroll
    for (int off = 1; off < 64; off <<= 1) {
        int u = __shfl_up(incl, off, 64);
        if (l >= off) incl += u;
    }
    if (l == 63) wsum[w] = incl;
    __syncthreads();
    if (t == 0) {
        int a = 0;
        #pragma unroll
        for (int i = 0; i < 8; i++) { woff[i] = a; a += wsum[i]; }
        part[blockIdx.x] = a;
    }
    __syncthreads();
    int excl = woff[w] + incl - v;
    if (node < N_NODES) start[node] = excl;   // block-local exclusive prefix
}

// ---- scan step 2: add scanned part[] offsets; finalize start and init cursor ----
__global__ __launch_bounds__(512) void k_scan2(
    const int* __restrict__ part, int* __restrict__ start, int* __restrict__ cursor)
{
    __shared__ int wsum[4], woff[4];
    __shared__ int sE[NSCAN];
    int t = threadIdx.x;
    int v = (t < NSCAN) ? part[t] : 0;
    int w = t >> 6, l = t & 63;
    int incl = v;
    #pragma unroll
    for (int off = 1; off < 64; off <<= 1) {
        int u = __shfl_up(incl, off, 64);
        if (l >= off) incl += u;
    }
    if (w < 4 && l == 63) wsum[w] = incl;
    __syncthreads();
    if (t == 0) {
        int a = 0;
        #pragma unroll
        for (int i = 0; i < 4; i++) { woff[i] = a; a += wsum[i]; }
    }
    __syncthreads();
    if (t < NSCAN) sE[t] = woff[w] + incl - v;   // exclusive prefix of part
    __syncthreads();
    int base = sE[blockIdx.x];
    int node = blockIdx.x * SCAN_BLK + t;
    if (node < N_NODES) {
        int s = start[node] + base;
        start[node] = s;
        cursor[node] = s;
    }
    if (blockIdx.x == 0 && t == 0) start[N_NODES] = E_EDGES;
}

// ---- direct CSR scatter: one pass, global atomic cursor per destination node ----
__global__ __launch_bounds__(512) void k_scatter(
    const int* __restrict__ ei, const float* __restrict__ ea,
    int* __restrict__ cursor, unsigned int* __restrict__ es)
{
    int i = (blockIdx.x * 512 + threadIdx.x) * 4;
    if (i >= E_EDGES) return;
    const int* dstp = ei + E_EDGES;
    if (i + 3 < E_EDGES) {
        int4 s4 = *(const int4*)(ei + i);
        int4 d4 = *(const int4*)(dstp + i);
        float4 a4 = *(const float4*)(ea + i);
        {
            int idx = atomicAdd(&cursor[d4.x], 1);
            unsigned int vq = (unsigned int)(a4.x * VQ_SCALE + 0.5f);
            es[idx] = (vq << SRC_BITS) | (unsigned int)s4.x;
        }
        {
            int idx = atomicAdd(&cursor[d4.y], 1);
            unsigned int vq = (unsigned int)(a4.y * VQ_SCALE + 0.5f);
            es[idx] = (vq << SRC_BITS) | (unsigned int)s4.y;
        }
        {
            int idx = atomicAdd(&cursor[d4.z], 1);
            unsigned int vq = (unsigned int)(a4.z * VQ_SCALE + 0.5f);
            es[idx] = (vq << SRC_BITS) | (unsigned int)s4.z;
        }
        {
            int idx = atomicAdd(&cursor[d4.w], 1);
            unsigned int vq = (unsigned int)(a4.w * VQ_SCALE + 0.5f);
            es[idx] = (vq << SRC_BITS) | (unsigned int)s4.w;
        }
    } else {
        for (int k = 0; k < 4; k++) {
            int e = i + k;
            if (e >= E_EDGES) break;
            int idx = atomicAdd(&cursor[dstp[e]], 1);
            unsigned int vq = (unsigned int)(ea[e] * VQ_SCALE + 0.5f);
            es[idx] = (vq << SRC_BITS) | (unsigned int)ei[e];
        }
    }
}

// ------- Aggregation layer 1 + fused proj2: 16 lanes/node; 8-way unrolled gather -------
__global__ __launch_bounds__(256) void k_agg1(
    const unsigned int* __restrict__ es, const int* __restrict__ start,
    const unsigned int* __restrict__ y, const float* __restrict__ r1,
    const float* __restrict__ W2, const float* __restrict__ root2,
    const float* __restrict__ b2,
    unsigned int* __restrict__ z, float* __restrict__ r2)
{
    __shared__ float sh[16 * 17];          // h tile: 16 nodes x 16 comps (stride 17)
    __shared__ float sW0[HID * NC], sW1[HID * NC], sRt[HID * NC], sB2[NC];
    int t = threadIdx.x;
    if (t < HID * NC) { sW0[t] = W2[t]; sW1[t] = W2[HID * NC + t]; sRt[t] = root2[t]; }
    if (t >= HID * NC && t < HID * NC + NC) sB2[t - HID * NC] = b2[t - HID * NC];

    int idx = blockIdx.x * 256 + t;
    int n = idx >> 4, o = idx & 15, g = t >> 4;
    if (n < N_NODES) {
        int j0 = start[n], j1 = start[n + 1];
        float acc0 = 0.f, acc1 = 0.f, acc2 = 0.f, acc3 = 0.f;
        int j = j0;
        for (; j + 7 < j1; j += 8) {
            unsigned int p0 = es[j],   p1 = es[j+1], p2 = es[j+2], p3 = es[j+3];
            unsigned int p4 = es[j+4], p5 = es[j+5], p6 = es[j+6], p7 = es[j+7];
            unsigned int q0 = y[(size_t)(p0 & SRC_MASK) * 16 + o];
            unsigned int q1 = y[(size_t)(p1 & SRC_MASK) * 16 + o];
            unsigned int q2 = y[(size_t)(p2 & SRC_MASK) * 16 + o];
            unsigned int q3 = y[(size_t)(p3 & SRC_MASK) * 16 + o];
            unsigned int q4 = y[(size_t)(p4 & SRC_MASK) * 16 + o];
            unsigned int q5 = y[(size_t)(p5 & SRC_MASK) * 16 + o];
            unsigned int q6 = y[(size_t)(p6 & SRC_MASK) * 16 + o];
            unsigned int q7 = y[(size_t)(p7 & SRC_MASK) * 16 + o];
            acc0 += lerp_pair(q0, (float)(p0 >> SRC_BITS) * (1.0f / VQ_SCALE));
            acc1 += lerp_pair(q1, (float)(p1 >> SRC_BITS) * (1.0f / VQ_SCALE));
            acc2 += lerp_pair(q2, (float)(p2 >> SRC_BITS) * (1.0f / VQ_SCALE));
            acc3 += lerp_pair(q3, (float)(p3 >> SRC_BITS) * (1.0f / VQ_SCALE));
            acc0 += lerp_pair(q4, (float)(p4 >> SRC_BITS) * (1.0f / VQ_SCALE));
            acc1 += lerp_pair(q5, (float)(p5 >> SRC_BITS) * (1.0f / VQ_SCALE));
            acc2 += lerp_pair(q6, (float)(p6 >> SRC_BITS) * (1.0f / VQ_SCALE));
            acc3 += lerp_pair(q7, (float)(p7 >> SRC_BITS) * (1.0f / VQ_SCALE));
        }
        for (; j + 3 < j1; j += 4) {
            unsigned int p0 = es[j], p1 = es[j+1], p2 = es[j+2], p3 = es[j+3];
            unsigned int q0 = y[(size_t)(p0 & SRC_MASK) * 16 + o];
            unsigned int q1 = y[(size_t)(p1 & SRC_MASK) * 16 + o];
            unsigned int q2 = y[(size_t)(p2 & SRC_MASK) * 16 + o];
            unsigned int q3 = y[(size_t)(p3 & SRC_MASK) * 16 + o];
            acc0 += lerp_pair(q0, (float)(p0 >> SRC_BITS) * (1.0f / VQ_SCALE));
            acc1 += lerp_pair(q1, (float)(p1 >> SRC_BITS) * (1.0f / VQ_SCALE));
            acc2 += lerp_pair(q2, (float)(p2 >> SRC_BITS) * (1.0f / VQ_SCALE));
            acc3 += lerp_pair(q3, (float)(p3 >> SRC_BITS) * (1.0f / VQ_SCALE));
        }
        for (; j < j1; j++) {
            unsigned int p = es[j];
            unsigned int q = y[(size_t)(p & SRC_MASK) * 16 + o];
            acc0 += lerp_pair(q, (float)(p >> SRC_BITS) * (1.0f / VQ_SCALE));
        }
        float acc = (acc0 + acc1) + (acc2 + acc3);
        float inv = 1.0f / fmaxf((float)(j1 - j0), 1.0f);
        float hv = acc * inv + r1[(size_t)n * HID + o];
        sh[g * 17 + o] = hv > 0.0f ? hv : expm1f(hv);   // elu -> LDS
    }
    __syncthreads();

    // epilogue: same 16 lanes/node compute proj2 from the LDS h tile
    int n2 = blockIdx.x * 16 + g;
    if (n2 < N_NODES) {
        int cc = o;
        unsigned int* pz = z + (size_t)n2 * 16;
        if (cc < NC) {
            float a0 = 0.f, a1 = 0.f, ar = sB2[cc];
            #pragma unroll
            for (int i = 0; i < HID; i++) {
                float hi = sh[g * 17 + i];
                a0 += hi * sW0[i * NC + cc];
                a1 += hi * sW1[i * NC + cc];
                ar += hi * sRt[i * NC + cc];
            }
            pz[cc] = bf16pair(a0, a1);
            r2[(size_t)n2 * NC + cc] = ar;
        } else {
            pz[cc] = 0u;
        }
    }
}

// -- Aggregation layer 2: 16 lanes/node; 8-way unrolled; fused mean+root+log_softmax --
__global__ __launch_bounds__(256) void k_agg2(
    const unsigned int* __restrict__ es, const int* __restrict__ start,
    const unsigned int* __restrict__ z,
    const float* __restrict__ r2, float* __restrict__ out)
{
    int idx = blockIdx.x * 256 + threadIdx.x;
    int n = idx >> 4, o = idx & 15;
    if (n >= N_NODES) return;
    int j0 = start[n], j1 = start[n + 1];
    float acc0 = 0.f, acc1 = 0.f, acc2 = 0.f, acc3 = 0.f;
    int j = j0;
    for (; j + 7 < j1; j += 8) {
        unsigned int p0 = es[j],   p1 = es[j+1], p2 = es[j+2], p3 = es[j+3];
        unsigned int p4 = es[j+4], p5 = es[j+5], p6 = es[j+6], p7 = es[j+7];
        unsigned int q0 = z[(size_t)(p0 & SRC_MASK) * 16 + o];
        unsigned int q1 = z[(size_t)(p1 & SRC_MASK) * 16 + o];
        unsigned int q2 = z[(size_t)(p2 & SRC_MASK) * 16 + o];
        unsigned int q3 = z[(size_t)(p3 & SRC_MASK) * 16 + o];
        unsigned int q4 = z[(size_t)(p4 & SRC_MASK) * 16 + o];
        unsigned int q5 = z[(size_t)(p5 & SRC_MASK) * 16 + o];
        unsigned int q6 = z[(size_t)(p6 & SRC_MASK) * 16 + o];
        unsigned int q7 = z[(size_t)(p7 & SRC_MASK) * 16 + o];
        acc0 += lerp_pair(q0, (float)(p0 >> SRC_BITS) * (1.0f / VQ_SCALE));
        acc1 += lerp_pair(q1, (float)(p1 >> SRC_BITS) * (1.0f / VQ_SCALE));
        acc2 += lerp_pair(q2, (float)(p2 >> SRC_BITS) * (1.0f / VQ_SCALE));
        acc3 += lerp_pair(q3, (float)(p3 >> SRC_BITS) * (1.0f / VQ_SCALE));
        acc0 += lerp_pair(q4, (float)(p4 >> SRC_BITS) * (1.0f / VQ_SCALE));
        acc1 += lerp_pair(q5, (float)(p5 >> SRC_BITS) * (1.0f / VQ_SCALE));
        acc2 += lerp_pair(q6, (float)(p6 >> SRC_BITS) * (1.0f / VQ_SCALE));
        acc3 += lerp_pair(q7, (float)(p7 >> SRC_BITS) * (1.0f / VQ_SCALE));
    }
    for (; j + 3 < j1; j += 4) {
        unsigned int p0 = es[j], p1 = es[j+1], p2 = es[j+2], p3 = es[j+3];
        unsigned int q0 = z[(size_t)(p0 & SRC_MASK) * 16 + o];
        unsigned int q1 = z[(size_t)(p1 & SRC_MASK) * 16 + o];
        unsigned int q2 = z[(size_t)(p2 & SRC_MASK) * 16 + o];
        unsigned int q3 = z[(size_t)(p3 & SRC_MASK) * 16 + o];
        acc0 += lerp_pair(q0, (float)(p0 >> SRC_BITS) * (1.0f / VQ_SCALE));
        acc1 += lerp_pair(q1, (float)(p1 >> SRC_BITS) * (1.0f / VQ_SCALE));
        acc2 += lerp_pair(q2, (float)(p2 >> SRC_BITS) * (1.0f / VQ_SCALE));
        acc3 += lerp_pair(q3, (float)(p3 >> SRC_BITS) * (1.0f / VQ_SCALE));
    }
    for (; j < j1; j++) {
        unsigned int p = es[j];
        unsigned int q = z[(size_t)(p & SRC_MASK) * 16 + o];
        acc0 += lerp_pair(q, (float)(p >> SRC_BITS) * (1.0f / VQ_SCALE));
    }
    float acc = (acc0 + acc1) + (acc2 + acc3);
    float val = -INFINITY;
    if (o < NC) {
        float inv = 1.0f / fmaxf((float)(j1 - j0), 1.0f);
        val = acc * inv + r2[(size_t)n * NC + o];
    }
    float mx = val;
    #pragma unroll
    for (int off = 8; off > 0; off >>= 1) mx = fmaxf(mx, __shfl_xor(mx, off, 16));
    float ex = (o < NC) ? expf(val - mx) : 0.0f;
    float ssum = ex;
    #pragma unroll
    for (int off = 8; off > 0; off >>= 1) ssum += __shfl_xor(ssum, off, 16);
    if (o < NC) out[(size_t)n * NC + o] = val - mx - logf(ssum);
}

extern "C" void kernel_launch(void* const* d_in, const int* in_sizes, int n_in,
                              void* d_out, int out_size, void* d_ws, size_t ws_size,
                              hipStream_t stream) {
    const float* x     = (const float*)d_in[0];
    const int*   ei    = (const int*)d_in[1];     // [2,E] src row then dst row
    const float* ea    = (const float*)d_in[2];   // [E,1]
    const float* W1    = (const float*)d_in[3];
    const float* root1 = (const float*)d_in[4];
    const float* b1    = (const float*)d_in[5];
    const float* W2    = (const float*)d_in[6];
    const float* root2 = (const float*)d_in[7];
    const float* b2    = (const float*)d_in[8];
    float* out = (float*)d_out;

    // Workspace layout (head offsets 16B-aligned; int tail 4B-aligned).
    char* wsb = (char*)d_ws;
    unsigned int* es     = (unsigned int*)wsb;                            // E * 4B
    unsigned int* y      = es + (size_t)E_EDGES;                          // 100k*16*4B
    float*        r1     = (float*)(y + (size_t)N_NODES * 16);            // 100k*16*4B
    unsigned int* z      = (unsigned int*)(r1 + (size_t)N_NODES * HID);   // 100k*16*4B
    float*        r2     = (float*)(z + (size_t)N_NODES * 16);            // 100k*10*4B
    int*          start  = (int*)(r2 + (size_t)N_NODES * NC);             // N+1
    int*          cursor = start + N_NODES + 1;                           // N
    int*          deg    = cursor + N_NODES;                              // N
    int*          part   = deg + N_NODES;                                 // NSCAN

    int aggGrid  = (N_NODES * 16 + 255) / 256;
    int scatGrid = (E_EDGES / 4 + 511) / 512;   // 782

    hipMemsetAsync(deg, 0, (size_t)N_NODES * sizeof(int), stream);
    fused_l1deg<<<NODE_GRID + NDBLK, 256, 0, stream>>>(x, W1, root1, b1, ei, y, r1, deg);
    k_scan1 <<<NSCAN, SCAN_BLK, 0, stream>>>(deg, start, part);
    k_scan2 <<<NSCAN, SCAN_BLK, 0, stream>>>(part, start, cursor);
    k_scatter<<<scatGrid, 512, 0, stream>>>(ei, ea, cursor, es);
    k_agg1  <<<aggGrid, 256, 0, stream>>>(es, start, y, r1, W2, root2, b2, z, r2);
    k_agg2  <<<aggGrid, 256, 0, stream>>>(es, start, z, r2, out);
}